// Round 9
// baseline (232.715 us; speedup 1.0000x reference)
//
#include <hip/hip_runtime.h>
#include <hip/hip_fp16.h>

#define N_NODES 100000
#define N_EDGES 1600000
#define IN_F 128
#define OUT_F 32
#define HEADS 2
#define HO 64  // HEADS*OUT_F

#define NBUCK2 1563          // bucket = dst >> 6 (64-node slices)
#define BIN_BLOCKS 250
#define BIN_THREADS 1024
#define EPB (N_EDGES / BIN_BLOCKS)   // 6400 edges per bin block (exact)
#define NV4 (EPB/4)                  // 1600 int4 loads per block
#define LCAPH 1216           // per-bucket edge capacity: mean 1024, +6 sigma (proven R3-R8)

typedef __attribute__((ext_vector_type(8))) _Float16 half8;
typedef __attribute__((ext_vector_type(4))) _Float16 half4v;
typedef __attribute__((ext_vector_type(4))) float    f32x4;

#define XPAD 136   // 128 halves + 8 pad -> 272B row stride: 16B-aligned, 8-bank spread

// feat = x @ W via fp16 MFMA (16x16x32). Block: 256 thr / 4 waves, 64 nodes x 64 cols.
// W (32 KB fp32, L2-hot) is cast+transposed into LDS per block.
__global__ __launch_bounds__(256) void feat_k(
                       const float* __restrict__ x, const float* __restrict__ W,
                       const float* __restrict__ attn_l, const float* __restrict__ attn_r,
                       __half* __restrict__ feat16, float* __restrict__ el, float* __restrict__ er){
  __shared__ __align__(16) _Float16 Ws[64*XPAD];   // 17.4 KB  (B: W^T[c][k] fp16)
  __shared__ __align__(16) _Float16 xs[64*XPAD];   // 17.4 KB  (A: x[n][k] fp16)
  int tid = threadIdx.x;
  int node0 = blockIdx.x*64;

  // stage W: fp32 [k][c] -> fp16 Ws[c][k]
  for (int i = tid; i < 2048; i += 256){
    int k = i >> 4, c4 = (i & 15)*4;
    float4 v = ((const float4*)W)[i];
    Ws[(c4+0)*XPAD + k] = (_Float16)v.x;
    Ws[(c4+1)*XPAD + k] = (_Float16)v.y;
    Ws[(c4+2)*XPAD + k] = (_Float16)v.z;
    Ws[(c4+3)*XPAD + k] = (_Float16)v.w;
  }
  // stage x tile, fp32 -> fp16
  for (int i = tid; i < 2048; i += 256){
    int ln = i >> 5, kq = i & 31;
    int n = node0 + ln;
    float4 v = (n < N_NODES) ? ((const float4*)x)[(size_t)n*32 + kq]
                             : make_float4(0.f,0.f,0.f,0.f);
    half4v hv = { (_Float16)v.x, (_Float16)v.y, (_Float16)v.z, (_Float16)v.w };
    *(half4v*)&xs[ln*XPAD + kq*4] = hv;
  }
  __syncthreads();

  int w = tid >> 6, lane = tid & 63;
  int row_base = w*16;
  int lr = lane & 15, lg = lane >> 4;
  f32x4 acc0 = {0.f,0.f,0.f,0.f}, acc1 = {0.f,0.f,0.f,0.f};
  f32x4 acc2 = {0.f,0.f,0.f,0.f}, acc3 = {0.f,0.f,0.f,0.f};

  #pragma unroll
  for (int kk = 0; kk < 4; ++kk){
    int ko = kk*32 + lg*8;
    half8 a  = *(const half8*)&xs[(row_base + lr)*XPAD + ko];
    half8 b0 = *(const half8*)&Ws[( 0 + lr)*XPAD + ko];
    half8 b1 = *(const half8*)&Ws[(16 + lr)*XPAD + ko];
    half8 b2 = *(const half8*)&Ws[(32 + lr)*XPAD + ko];
    half8 b3 = *(const half8*)&Ws[(48 + lr)*XPAD + ko];
    acc0 = __builtin_amdgcn_mfma_f32_16x16x32_f16(a, b0, acc0, 0, 0, 0);
    acc1 = __builtin_amdgcn_mfma_f32_16x16x32_f16(a, b1, acc1, 0, 0, 0);
    acc2 = __builtin_amdgcn_mfma_f32_16x16x32_f16(a, b2, acc2, 0, 0, 0);
    acc3 = __builtin_amdgcn_mfma_f32_16x16x32_f16(a, b3, acc3, 0, 0, 0);
  }

  float al0 = attn_l[ 0 + lr], al1 = attn_l[16 + lr];
  float al2 = attn_l[32 + lr], al3 = attn_l[48 + lr];
  float ar0 = attn_r[ 0 + lr], ar1 = attn_r[16 + lr];
  float ar2 = attn_r[32 + lr], ar3 = attn_r[48 + lr];

  #pragma unroll
  for (int r = 0; r < 4; ++r){
    int n = node0 + row_base + lg*4 + r;
    float f0 = acc0[r], f1 = acc1[r], f2 = acc2[r], f3 = acc3[r];
    float p0 = f0*al0 + f1*al1, p1 = f2*al2 + f3*al3;
    float q0 = f0*ar0 + f1*ar1, q1 = f2*ar2 + f3*ar3;
    #pragma unroll
    for (int off = 1; off < 16; off <<= 1){
      p0 += __shfl_xor(p0, off); p1 += __shfl_xor(p1, off);
      q0 += __shfl_xor(q0, off); q1 += __shfl_xor(q1, off);
    }
    if (n < N_NODES){
      size_t base = (size_t)n*HO;
      feat16[base +  0 + lr] = __float2half_rn(f0);
      feat16[base + 16 + lr] = __float2half_rn(f1);
      feat16[base + 32 + lr] = __float2half_rn(f2);
      feat16[base + 48 + lr] = __float2half_rn(f3);
      if (lr == 0){
        *(float2*)&el[n*HEADS] = make_float2(p0, p1);
        *(float2*)&er[n*HEADS] = make_float2(q0, q1);
      }
    }
  }
}

// Fused bin: count -> in-LDS scan -> place. int4-vectorized edge loads,
// all el/er gathers issued before compute. Block-major dense CSR:
// block blk owns stg[blk*EPB .. +EPB) exclusively.
__global__ __launch_bounds__(1024) void binB_k(const int* __restrict__ src,
                      const int* __restrict__ dst,
                      const float* __restrict__ el, const float* __restrict__ er,
                      const float* __restrict__ b1, const float* __restrict__ W2,
                      const float* __restrict__ b2,
                      int* __restrict__ bstart, float* __restrict__ ccomb,
                      uint2* __restrict__ stg){
  __shared__ int cnt[NBUCK2];
  int tid = threadIdx.x, blk = blockIdx.x;
  int lane = tid & 63, w = tid >> 6;
  if (blk == 0 && tid == 0){
    float a = 0.f;
    for (int k = 0; k < OUT_F; ++k) a = fmaf(b1[k], W2[k], a);
    *ccomb = a + b2[0];
  }
  for (int i = tid; i < NBUCK2; i += BIN_THREADS) cnt[i] = 0;
  __syncthreads();

  // load up to 8 edges per thread (2 x int4), batched
  int s_[8], d_[8];
  int ne = 0;
  const int4* s4p = (const int4*)(src + blk*EPB);
  const int4* d4p = (const int4*)(dst + blk*EPB);
  #pragma unroll
  for (int u = 0; u < 2; ++u){
    int i4 = tid + u*BIN_THREADS;
    if (i4 < NV4){
      int4 sv = s4p[i4], dv = d4p[i4];
      s_[4*u+0]=sv.x; s_[4*u+1]=sv.y; s_[4*u+2]=sv.z; s_[4*u+3]=sv.w;
      d_[4*u+0]=dv.x; d_[4*u+1]=dv.y; d_[4*u+2]=dv.z; d_[4*u+3]=dv.w;
      ne = 4*u+4;
    }
  }
  // issue all gathers (independent)
  float2 elv[8], erv[8];
  #pragma unroll
  for (int i = 0; i < 8; ++i){
    if (i < ne){
      elv[i] = *(const float2*)&el[s_[i]*HEADS];
      erv[i] = *(const float2*)&er[d_[i]*HEADS];
    }
  }
  // compute records + count
  unsigned rx[8], rex[8]; int rb[8];
  #pragma unroll
  for (int i = 0; i < 8; ++i){
    if (i < ne){
      float t0 = elv[i].x + erv[i].x, t1 = elv[i].y + erv[i].y;
      t0 = t0 > 0.f ? t0 : 0.2f*t0;
      t1 = t1 > 0.f ? t1 : 0.2f*t1;
      __half2 ex2 = __float22half2_rn(make_float2(__expf(t0), __expf(t1)));
      rb[i] = d_[i] >> 6;
      rx[i] = ((unsigned)s_[i] << 6) | (unsigned)(d_[i] & 63);
      rex[i] = *(const unsigned*)&ex2;
      atomicAdd(&cnt[rb[i]], 1);
    }
  }
  __syncthreads();

  // exclusive scan of cnt[NBUCK2] in place (wave 0, chunks of 64)
  if (w == 0){
    int run = 0;
    for (int c = 0; c < NBUCK2; c += 64){
      int i = c + lane;
      int v = (i < NBUCK2) ? cnt[i] : 0;
      int inc = v;
      #pragma unroll
      for (int off = 1; off < 64; off <<= 1){
        int t = __shfl_up(inc, off);
        if (lane >= off) inc += t;
      }
      if (i < NBUCK2) cnt[i] = run + inc - v;
      run += __shfl(inc, 63);
    }
  }
  __syncthreads();

  // emit per-block offsets (coalesced)
  for (int i = tid; i < NBUCK2; i += BIN_THREADS)
    bstart[(size_t)blk*NBUCK2 + i] = cnt[i];
  __syncthreads();   // all reads of cnt done before phase 2 mutates it

  // place records (cnt reused as cursor)
  #pragma unroll
  for (int i = 0; i < 8; ++i){
    if (i < ne){
      int pos = atomicAdd(&cnt[rb[i]], 1);
      stg[(size_t)blk*EPB + pos] = make_uint2(rx[i], rex[i]);
    }
  }
}

// Fused scatter + aggregate, v8: single global pass staging (R8), aggregate
// remapped to 8-lane edge groups (uint4 feature gather = 8 halves/lane):
// chunk = 8 edges -> ~20% slot waste (vs 37% at 16), software-pipelined
// prefetch of next chunk's record+gather under current chunk's FMAs.
__global__ void __launch_bounds__(512, 8) scatter_agg_k(
                              const int* __restrict__ bstart, const uint2* __restrict__ stg,
                              const __half* __restrict__ feat16, const float* __restrict__ bias,
                              const float* __restrict__ W1, const float* __restrict__ W2,
                              float* __restrict__ s1, float* __restrict__ s2){
  __shared__ uint2 lraw[LCAPH];      // 9.5 KB
  __shared__ uint2 lsev[LCAPH];      // 9.5 KB
  __shared__ int soff[BIN_BLOCKS];
  __shared__ int send[BIN_BLOCKS];
  __shared__ int segb[BIN_BLOCKS];
  __shared__ float wc[64];
  __shared__ int hist[64];
  __shared__ int start_[64];
  __shared__ int cur[64];
  __shared__ int wtot[4];
  int b = blockIdx.x;
  int tid = threadIdx.x;
  int w = tid >> 6, lane = tid & 63;
  if (tid < 64){
    hist[tid] = 0;
    float a = 0.f;
    #pragma unroll
    for (int k = 0; k < OUT_F; ++k) a = fmaf(W1[tid*OUT_F + k], W2[k], a);
    wc[tid] = a;
  }
  for (int i = tid; i < BIN_BLOCKS; i += 512){
    int o = bstart[(size_t)i*NBUCK2 + b];
    int e = (b == NBUCK2-1) ? EPB : bstart[(size_t)i*NBUCK2 + b + 1];
    soff[i] = o; send[i] = e;
  }
  __syncthreads();

  // hierarchical exclusive scan of segment lengths -> segb
  int c_ = 0, inc = 0;
  if (tid < 256){
    if (tid < BIN_BLOCKS) c_ = send[tid] - soff[tid];
    inc = c_;
    #pragma unroll
    for (int off = 1; off < 64; off <<= 1){
      int t = __shfl_up(inc, off);
      if (lane >= off) inc += t;
    }
    if (lane == 63) wtot[w] = inc;
  }
  __syncthreads();
  if (tid == 0){
    int r = 0;
    #pragma unroll
    for (int i2 = 0; i2 < 4; ++i2){ int t = wtot[i2]; wtot[i2] = r; r += t; }
  }
  __syncthreads();
  if (tid < BIN_BLOCKS) segb[tid] = wtot[w] + inc - c_;
  __syncthreads();

  // compact copy global -> lraw (exact offsets, no atomics) + fused histogram
  int grp = tid >> 3, gl = tid & 7;
  for (int sg = grp; sg < BIN_BLOCKS; sg += 64){
    const uint2* seg = stg + (size_t)sg*EPB;
    int o = soff[sg], e = send[sg];
    int base = segb[sg] - o;
    for (int j = o + gl; j < e; j += 8){
      uint2 r = seg[j];
      int p = base + j;
      if (p < LCAPH){
        lraw[p] = r;
        atomicAdd(&hist[r.x & 63], 1);
      }
    }
  }
  __syncthreads();

  // exclusive scan of hist[64] (wave 0)
  if (tid < 64){
    int v = hist[tid];
    int inc2 = v;
    #pragma unroll
    for (int off = 1; off < 64; off <<= 1){
      int t = __shfl_up(inc2, off);
      if (lane >= off) inc2 += t;
    }
    start_[tid] = inc2 - v;
    cur[tid] = inc2 - v;
  }
  __syncthreads();

  // LDS reorder raw -> sorted by local node
  int tot = segb[BIN_BLOCKS-1] + (send[BIN_BLOCKS-1] - soff[BIN_BLOCKS-1]);
  if (tot > LCAPH) tot = LCAPH;
  for (int i = tid; i < tot; i += 512){
    uint2 r = lraw[i];
    int pos = atomicAdd(&cur[r.x & 63], 1);
    lsev[pos] = make_uint2(r.x >> 6, r.y);
  }
  __syncthreads();

  // aggregate: wave w handles local nodes w*8 .. w*8+7.
  // lane = g*8 + c8: g = edge slot (8 edges/chunk), c8 = feature octet.
  int g  = lane >> 3;
  int c8 = lane & 7;
  int h  = (c8 >= 4);
  float4 bv03 = *(const float4*)&bias[c8*8];
  float4 bv47 = *(const float4*)&bias[c8*8 + 4];
  int wo = (h ? 32 : 0) + (c8 & 3)*8;
  float m0 = wc[wo+0], m1 = wc[wo+1], m2 = wc[wo+2], m3 = wc[wo+3];
  float m4 = wc[wo+4], m5 = wc[wo+5], m6 = wc[wo+6], m7 = wc[wo+7];
  unsigned co = (unsigned)(c8*8);
  for (int i = 0; i < 8; ++i){
    int nl = w*8 + i;
    int node = b*64 + nl;
    if (node >= N_NODES) break;
    int s0 = start_[nl];
    int e0 = cur[nl]; if (e0 > LCAPH) e0 = LCAPH;
    int deg = e0 - s0; if (deg < 0) deg = 0;

    float a0=0.f, a1=0.f, a2=0.f, a3=0.f, a4=0.f, a5=0.f, a6=0.f, a7=0.f, dn=0.f;
    if (deg > 0){
      // prologue: load slot for chunk 0
      float alc = 0.f; unsigned snc = 0;
      if (g < deg){ uint2 r = lsev[s0 + g]; snc = r.x;
        alc = __half2float(((const __half*)&r.y)[h]); }
      uint4 vc = *(const uint4*)(feat16 + ((snc << 6) + co));
      for (int j0 = 0; j0 < deg; j0 += 8){
        // prefetch next chunk's record + feature gather
        float aln = 0.f; unsigned snn = 0;
        int jn = j0 + 8 + g;
        if (jn < deg){ uint2 r = lsev[s0 + jn]; snn = r.x;
          aln = __half2float(((const __half*)&r.y)[h]); }
        uint4 vn = *(const uint4*)(feat16 + ((snn << 6) + co));
        // compute current chunk
        dn += alc;
        float2 f01 = __half22float2(*(const __half2*)&vc.x);
        float2 f23 = __half22float2(*(const __half2*)&vc.y);
        float2 f45 = __half22float2(*(const __half2*)&vc.z);
        float2 f67 = __half22float2(*(const __half2*)&vc.w);
        a0 = fmaf(alc, f01.x, a0); a1 = fmaf(alc, f01.y, a1);
        a2 = fmaf(alc, f23.x, a2); a3 = fmaf(alc, f23.y, a3);
        a4 = fmaf(alc, f45.x, a4); a5 = fmaf(alc, f45.y, a5);
        a6 = fmaf(alc, f67.x, a6); a7 = fmaf(alc, f67.y, a7);
        alc = aln; vc = vn;
      }
    }
    // reduce over the 8 edge groups (lane bits 3..5)
    #pragma unroll
    for (int off = 8; off < 64; off <<= 1){
      a0 += __shfl_xor(a0, off); a1 += __shfl_xor(a1, off);
      a2 += __shfl_xor(a2, off); a3 += __shfl_xor(a3, off);
      a4 += __shfl_xor(a4, off); a5 += __shfl_xor(a5, off);
      a6 += __shfl_xor(a6, off); a7 += __shfl_xor(a7, off);
      dn += __shfl_xor(dn, off);
    }
    float rh = dn > 0.f ? 1.f/dn : 0.f;   // deferred softmax divide
    a0 = fmaf(a0, rh, bv03.x); a1 = fmaf(a1, rh, bv03.y);
    a2 = fmaf(a2, rh, bv03.z); a3 = fmaf(a3, rh, bv03.w);
    a4 = fmaf(a4, rh, bv47.x); a5 = fmaf(a5, rh, bv47.y);
    a6 = fmaf(a6, rh, bv47.z); a7 = fmaf(a7, rh, bv47.w);
    // head mean: lane c8 <-> c8^4 pairs feature f with f+32
    float h0 = 0.5f*(a0 + __shfl_xor(a0, 4)); h0 = fmaxf(h0, 0.f);
    float h1 = 0.5f*(a1 + __shfl_xor(a1, 4)); h1 = fmaxf(h1, 0.f);
    float h2 = 0.5f*(a2 + __shfl_xor(a2, 4)); h2 = fmaxf(h2, 0.f);
    float h3 = 0.5f*(a3 + __shfl_xor(a3, 4)); h3 = fmaxf(h3, 0.f);
    float h4 = 0.5f*(a4 + __shfl_xor(a4, 4)); h4 = fmaxf(h4, 0.f);
    float h5 = 0.5f*(a5 + __shfl_xor(a5, 4)); h5 = fmaxf(h5, 0.f);
    float h6 = 0.5f*(a6 + __shfl_xor(a6, 4)); h6 = fmaxf(h6, 0.f);
    float h7 = 0.5f*(a7 + __shfl_xor(a7, 4)); h7 = fmaxf(h7, 0.f);
    float r = h0*m0 + h1*m1 + h2*m2 + h3*m3 + h4*m4 + h5*m5 + h6*m6 + h7*m7;
    r += __shfl_xor(r, 1); r += __shfl_xor(r, 2);
    if (lane == 0)      s1[node] = r;
    else if (lane == 4) s2[node] = r;
  }
}

// 8 edges per thread -> 16 independent gathers in flight.
__global__ __launch_bounds__(256) void edge_score_k(
                             const int* __restrict__ src, const int* __restrict__ dst,
                             const float* __restrict__ s1, const float* __restrict__ s2,
                             const float* __restrict__ ccomb, float* __restrict__ out){
  int i = blockIdx.x*blockDim.x + threadIdx.x;
  if (i >= N_EDGES/8) return;
  int4 sa = ((const int4*)src)[2*i],   sb = ((const int4*)src)[2*i+1];
  int4 da = ((const int4*)dst)[2*i],   db = ((const int4*)dst)[2*i+1];
  float v0 = s1[sa.x], v1 = s1[sa.y], v2 = s1[sa.z], v3 = s1[sa.w];
  float v4 = s1[sb.x], v5 = s1[sb.y], v6 = s1[sb.z], v7 = s1[sb.w];
  float u0 = s2[da.x], u1 = s2[da.y], u2 = s2[da.z], u3 = s2[da.w];
  float u4 = s2[db.x], u5 = s2[db.y], u6 = s2[db.z], u7 = s2[db.w];
  float c = ccomb[0];
  float4 oa, ob;
  oa.x = v0+u0+c; oa.y = v1+u1+c; oa.z = v2+u2+c; oa.w = v3+u3+c;
  ob.x = v4+u4+c; ob.y = v5+u5+c; ob.z = v6+u6+c; ob.w = v7+u7+c;
  ((float4*)out)[2*i]   = oa;
  ((float4*)out)[2*i+1] = ob;
}

extern "C" void kernel_launch(void* const* d_in, const int* in_sizes, int n_in,
                              void* d_out, int out_size, void* d_ws, size_t ws_size,
                              hipStream_t stream){
  const float* x      = (const float*)d_in[0];
  const float* W      = (const float*)d_in[1];
  const float* attn_l = (const float*)d_in[2];
  const float* attn_r = (const float*)d_in[3];
  const float* bias   = (const float*)d_in[4];
  const float* W1     = (const float*)d_in[5];
  const float* b1     = (const float*)d_in[6];
  const float* W2     = (const float*)d_in[7];
  const float* b2     = (const float*)d_in[8];
  const int*   src    = (const int*)d_in[9];
  const int*   dst    = (const int*)d_in[10];
  float* out = (float*)d_out;

  float* ws = (float*)d_ws;
  size_t off = 0;
  __half* feat16 = (__half*)(ws + off); off += (size_t)N_NODES*HO/2;
  float*  el     = ws + off; off += (size_t)N_NODES*HEADS;
  float*  er     = ws + off; off += (size_t)N_NODES*HEADS;
  float*  s1     = ws + off; off += N_NODES;
  float*  s2     = ws + off; off += N_NODES;
  float*  ccomb  = ws + off; off += 64;
  int*    bstart = (int*)(ws + off); off += (size_t)BIN_BLOCKS*NBUCK2;
  off = (off + 1) & ~(size_t)1;  // 8B align
  uint2*  stg    = (uint2*)(ws + off); off += (size_t)2*N_EDGES;

  feat_k<<<(N_NODES + 63)/64, 256, 0, stream>>>(x, W, attn_l, attn_r, feat16, el, er);
  binB_k<<<BIN_BLOCKS, BIN_THREADS, 0, stream>>>(src, dst, el, er, b1, W2, b2,
                                                 bstart, ccomb, stg);
  scatter_agg_k<<<NBUCK2, 512, 0, stream>>>(bstart, stg, feat16, bias, W1, W2, s1, s2);
  edge_score_k<<<(N_EDGES/8 + 255)/256, 256, 0, stream>>>(src, dst, s1, s2, ccomb, out);
}

// Round 10
// 220.002 us; speedup vs baseline: 1.0578x; 1.0578x over previous
//
#include <hip/hip_runtime.h>
#include <hip/hip_fp16.h>

#define N_NODES 100000
#define N_EDGES 1600000
#define IN_F 128
#define OUT_F 32
#define HEADS 2
#define HO 64  // HEADS*OUT_F

#define NBUCK2 1563          // bucket = dst >> 6 (64-node slices)
#define BIN_BLOCKS 250
#define BIN_THREADS 1024
#define EPB (N_EDGES / BIN_BLOCKS)   // 6400 edges per bin block (exact)
#define NV4 (EPB/4)                  // 1600 int4 loads per block
#define LCAPH 1216           // per-bucket edge capacity: mean 1024, +6 sigma (proven R3-R8)

typedef __attribute__((ext_vector_type(8))) _Float16 half8;
typedef __attribute__((ext_vector_type(4))) _Float16 half4v;
typedef __attribute__((ext_vector_type(4))) float    f32x4;

#define XPAD 136   // 128 halves + 8 pad -> 272B row stride: 16B-aligned, 8-bank spread

// feat = x @ W via fp16 MFMA (16x16x32). Block: 256 thr / 4 waves, 64 nodes x 64 cols.
// W (32 KB fp32, L2-hot) is cast+transposed into LDS per block.
__global__ __launch_bounds__(256) void feat_k(
                       const float* __restrict__ x, const float* __restrict__ W,
                       const float* __restrict__ attn_l, const float* __restrict__ attn_r,
                       __half* __restrict__ feat16, float* __restrict__ el, float* __restrict__ er){
  __shared__ __align__(16) _Float16 Ws[64*XPAD];   // 17.4 KB  (B: W^T[c][k] fp16)
  __shared__ __align__(16) _Float16 xs[64*XPAD];   // 17.4 KB  (A: x[n][k] fp16)
  int tid = threadIdx.x;
  int node0 = blockIdx.x*64;

  // stage W: fp32 [k][c] -> fp16 Ws[c][k]
  for (int i = tid; i < 2048; i += 256){
    int k = i >> 4, c4 = (i & 15)*4;
    float4 v = ((const float4*)W)[i];
    Ws[(c4+0)*XPAD + k] = (_Float16)v.x;
    Ws[(c4+1)*XPAD + k] = (_Float16)v.y;
    Ws[(c4+2)*XPAD + k] = (_Float16)v.z;
    Ws[(c4+3)*XPAD + k] = (_Float16)v.w;
  }
  // stage x tile, fp32 -> fp16
  for (int i = tid; i < 2048; i += 256){
    int ln = i >> 5, kq = i & 31;
    int n = node0 + ln;
    float4 v = (n < N_NODES) ? ((const float4*)x)[(size_t)n*32 + kq]
                             : make_float4(0.f,0.f,0.f,0.f);
    half4v hv = { (_Float16)v.x, (_Float16)v.y, (_Float16)v.z, (_Float16)v.w };
    *(half4v*)&xs[ln*XPAD + kq*4] = hv;
  }
  __syncthreads();

  int w = tid >> 6, lane = tid & 63;
  int row_base = w*16;
  int lr = lane & 15, lg = lane >> 4;
  f32x4 acc0 = {0.f,0.f,0.f,0.f}, acc1 = {0.f,0.f,0.f,0.f};
  f32x4 acc2 = {0.f,0.f,0.f,0.f}, acc3 = {0.f,0.f,0.f,0.f};

  #pragma unroll
  for (int kk = 0; kk < 4; ++kk){
    int ko = kk*32 + lg*8;
    half8 a  = *(const half8*)&xs[(row_base + lr)*XPAD + ko];
    half8 b0 = *(const half8*)&Ws[( 0 + lr)*XPAD + ko];
    half8 b1 = *(const half8*)&Ws[(16 + lr)*XPAD + ko];
    half8 b2 = *(const half8*)&Ws[(32 + lr)*XPAD + ko];
    half8 b3 = *(const half8*)&Ws[(48 + lr)*XPAD + ko];
    acc0 = __builtin_amdgcn_mfma_f32_16x16x32_f16(a, b0, acc0, 0, 0, 0);
    acc1 = __builtin_amdgcn_mfma_f32_16x16x32_f16(a, b1, acc1, 0, 0, 0);
    acc2 = __builtin_amdgcn_mfma_f32_16x16x32_f16(a, b2, acc2, 0, 0, 0);
    acc3 = __builtin_amdgcn_mfma_f32_16x16x32_f16(a, b3, acc3, 0, 0, 0);
  }

  float al0 = attn_l[ 0 + lr], al1 = attn_l[16 + lr];
  float al2 = attn_l[32 + lr], al3 = attn_l[48 + lr];
  float ar0 = attn_r[ 0 + lr], ar1 = attn_r[16 + lr];
  float ar2 = attn_r[32 + lr], ar3 = attn_r[48 + lr];

  #pragma unroll
  for (int r = 0; r < 4; ++r){
    int n = node0 + row_base + lg*4 + r;
    float f0 = acc0[r], f1 = acc1[r], f2 = acc2[r], f3 = acc3[r];
    float p0 = f0*al0 + f1*al1, p1 = f2*al2 + f3*al3;
    float q0 = f0*ar0 + f1*ar1, q1 = f2*ar2 + f3*ar3;
    #pragma unroll
    for (int off = 1; off < 16; off <<= 1){
      p0 += __shfl_xor(p0, off); p1 += __shfl_xor(p1, off);
      q0 += __shfl_xor(q0, off); q1 += __shfl_xor(q1, off);
    }
    if (n < N_NODES){
      size_t base = (size_t)n*HO;
      feat16[base +  0 + lr] = __float2half_rn(f0);
      feat16[base + 16 + lr] = __float2half_rn(f1);
      feat16[base + 32 + lr] = __float2half_rn(f2);
      feat16[base + 48 + lr] = __float2half_rn(f3);
      if (lr == 0){
        *(float2*)&el[n*HEADS] = make_float2(p0, p1);
        *(float2*)&er[n*HEADS] = make_float2(q0, q1);
      }
    }
  }
}

// Fused bin: count -> in-LDS scan -> place. int4-vectorized edge loads,
// all el/er gathers issued before compute. Block-major dense CSR:
// block blk owns stg[blk*EPB .. +EPB) exclusively. Block 0 also folds
// wcomb = W1@W2 and ccomb = b1.W2+b2. bstart written TRANSPOSED
// (bucket-major rows) so scatter reads it coalesced.
__global__ __launch_bounds__(1024) void binB_k(const int* __restrict__ src,
                      const int* __restrict__ dst,
                      const float* __restrict__ el, const float* __restrict__ er,
                      const float* __restrict__ W1, const float* __restrict__ b1,
                      const float* __restrict__ W2, const float* __restrict__ b2,
                      int* __restrict__ bstartT, float* __restrict__ wcomb,
                      float* __restrict__ ccomb, uint2* __restrict__ stg){
  __shared__ int cnt[NBUCK2];
  int tid = threadIdx.x, blk = blockIdx.x;
  int lane = tid & 63, w = tid >> 6;
  if (blk == 0){
    if (tid < HO){
      float a = 0.f;
      for (int k = 0; k < OUT_F; ++k) a = fmaf(W1[tid*OUT_F + k], W2[k], a);
      wcomb[tid] = a;
    }
    if (tid == HO){
      float a = 0.f;
      for (int k = 0; k < OUT_F; ++k) a = fmaf(b1[k], W2[k], a);
      *ccomb = a + b2[0];
    }
  }
  for (int i = tid; i < NBUCK2; i += BIN_THREADS) cnt[i] = 0;
  __syncthreads();

  // load up to 8 edges per thread (2 x int4), batched
  int s_[8], d_[8];
  int ne = 0;
  const int4* s4p = (const int4*)(src + blk*EPB);
  const int4* d4p = (const int4*)(dst + blk*EPB);
  #pragma unroll
  for (int u = 0; u < 2; ++u){
    int i4 = tid + u*BIN_THREADS;
    if (i4 < NV4){
      int4 sv = s4p[i4], dv = d4p[i4];
      s_[4*u+0]=sv.x; s_[4*u+1]=sv.y; s_[4*u+2]=sv.z; s_[4*u+3]=sv.w;
      d_[4*u+0]=dv.x; d_[4*u+1]=dv.y; d_[4*u+2]=dv.z; d_[4*u+3]=dv.w;
      ne = 4*u+4;
    }
  }
  // issue all gathers (independent)
  float2 elv[8], erv[8];
  #pragma unroll
  for (int i = 0; i < 8; ++i){
    if (i < ne){
      elv[i] = *(const float2*)&el[s_[i]*HEADS];
      erv[i] = *(const float2*)&er[d_[i]*HEADS];
    }
  }
  // compute records + count
  unsigned rx[8], rex[8]; int rb[8];
  #pragma unroll
  for (int i = 0; i < 8; ++i){
    if (i < ne){
      float t0 = elv[i].x + erv[i].x, t1 = elv[i].y + erv[i].y;
      t0 = t0 > 0.f ? t0 : 0.2f*t0;
      t1 = t1 > 0.f ? t1 : 0.2f*t1;
      __half2 ex2 = __float22half2_rn(make_float2(__expf(t0), __expf(t1)));
      rb[i] = d_[i] >> 6;
      rx[i] = ((unsigned)s_[i] << 6) | (unsigned)(d_[i] & 63);
      rex[i] = *(const unsigned*)&ex2;
      atomicAdd(&cnt[rb[i]], 1);
    }
  }
  __syncthreads();

  // exclusive scan of cnt[NBUCK2] in place (wave 0, chunks of 64)
  if (w == 0){
    int run = 0;
    for (int c = 0; c < NBUCK2; c += 64){
      int i = c + lane;
      int v = (i < NBUCK2) ? cnt[i] : 0;
      int inc = v;
      #pragma unroll
      for (int off = 1; off < 64; off <<= 1){
        int t = __shfl_up(inc, off);
        if (lane >= off) inc += t;
      }
      if (i < NBUCK2) cnt[i] = run + inc - v;
      run += __shfl(inc, 63);
    }
  }
  __syncthreads();

  // emit per-block offsets, transposed (bucket-major rows)
  for (int i = tid; i < NBUCK2; i += BIN_THREADS)
    bstartT[(size_t)i*BIN_BLOCKS + blk] = cnt[i];
  __syncthreads();   // all reads of cnt done before phase 2 mutates it

  // place records (cnt reused as cursor)
  #pragma unroll
  for (int i = 0; i < 8; ++i){
    if (i < ne){
      int pos = atomicAdd(&cnt[rb[i]], 1);
      stg[(size_t)blk*EPB + pos] = make_uint2(rx[i], rex[i]);
    }
  }
}

// Fused scatter + aggregate (R8 structure): single global pass staging,
// 16-lane feature groups x 4 edge slots. Prologue now reads wcomb (64 floats)
// and two coalesced bstartT rows instead of 500 scattered columns.
__global__ void __launch_bounds__(512, 8) scatter_agg_k(
                              const int* __restrict__ bstartT, const uint2* __restrict__ stg,
                              const __half* __restrict__ feat16, const float* __restrict__ bias,
                              const float* __restrict__ wcomb,
                              float* __restrict__ s1, float* __restrict__ s2){
  __shared__ uint2 lraw[LCAPH];      // 9.5 KB
  __shared__ uint2 lsev[LCAPH];      // 9.5 KB
  __shared__ int soff[BIN_BLOCKS];
  __shared__ int send[BIN_BLOCKS];
  __shared__ int segb[BIN_BLOCKS];
  __shared__ float wc[64];
  __shared__ int hist[64];
  __shared__ int start_[64];
  __shared__ int cur[64];
  __shared__ int wtot[4];
  int b = blockIdx.x;
  int tid = threadIdx.x;
  int w = tid >> 6, lane = tid & 63;
  if (tid < 64){
    hist[tid] = 0;
    wc[tid] = wcomb[tid];
  }
  for (int i = tid; i < BIN_BLOCKS; i += 512){
    soff[i] = bstartT[(size_t)b*BIN_BLOCKS + i];
    send[i] = (b == NBUCK2-1) ? EPB : bstartT[(size_t)(b+1)*BIN_BLOCKS + i];
  }
  __syncthreads();

  // hierarchical exclusive scan of segment lengths -> segb
  int c_ = 0, inc = 0;
  if (tid < 256){
    if (tid < BIN_BLOCKS) c_ = send[tid] - soff[tid];
    inc = c_;
    #pragma unroll
    for (int off = 1; off < 64; off <<= 1){
      int t = __shfl_up(inc, off);
      if (lane >= off) inc += t;
    }
    if (lane == 63) wtot[w] = inc;
  }
  __syncthreads();
  if (tid == 0){
    int r = 0;
    #pragma unroll
    for (int i2 = 0; i2 < 4; ++i2){ int t = wtot[i2]; wtot[i2] = r; r += t; }
  }
  __syncthreads();
  if (tid < BIN_BLOCKS) segb[tid] = wtot[w] + inc - c_;
  __syncthreads();

  // compact copy global -> lraw (exact offsets, no atomics) + fused histogram
  int grp = tid >> 3, gl = tid & 7;
  for (int sg = grp; sg < BIN_BLOCKS; sg += 64){
    const uint2* seg = stg + (size_t)sg*EPB;
    int o = soff[sg], e = send[sg];
    int base = segb[sg] - o;
    for (int j = o + gl; j < e; j += 8){
      uint2 r = seg[j];
      int p = base + j;
      if (p < LCAPH){
        lraw[p] = r;
        atomicAdd(&hist[r.x & 63], 1);
      }
    }
  }
  __syncthreads();

  // exclusive scan of hist[64] (wave 0)
  if (tid < 64){
    int v = hist[tid];
    int inc2 = v;
    #pragma unroll
    for (int off = 1; off < 64; off <<= 1){
      int t = __shfl_up(inc2, off);
      if (lane >= off) inc2 += t;
    }
    start_[tid] = inc2 - v;
    cur[tid] = inc2 - v;
  }
  __syncthreads();

  // LDS reorder raw -> sorted by local node
  int tot = segb[BIN_BLOCKS-1] + (send[BIN_BLOCKS-1] - soff[BIN_BLOCKS-1]);
  if (tot > LCAPH) tot = LCAPH;
  for (int i = tid; i < tot; i += 512){
    uint2 r = lraw[i];
    int pos = atomicAdd(&cur[r.x & 63], 1);
    lsev[pos] = make_uint2(r.x >> 6, r.y);
  }
  __syncthreads();

  // aggregate: wave w handles local nodes w*8 .. w*8+7; 16 edges in flight.
  int g  = lane >> 4;
  int c4 = lane & 15;
  int h  = (c4 >= 8);
  float b0v = bias[c4*4 + 0], b1v = bias[c4*4 + 1], b2v = bias[c4*4 + 2], b3v = bias[c4*4 + 3];
  int f0 = (c4 & 7)*4;
  int wo = (h ? 32 : 0) + f0;   // lanes c4<8 compute MLP row 0 (s1), c4>=8 row 1 (s2)
  float m0 = wc[wo], m1 = wc[wo+1], m2 = wc[wo+2], m3 = wc[wo+3];
  unsigned co = (unsigned)(c4*4);
  for (int i = 0; i < 8; ++i){
    int nl = w*8 + i;
    int node = b*64 + nl;
    if (node >= N_NODES) break;
    int s0 = start_[nl];
    int e0 = cur[nl]; if (e0 > LCAPH) e0 = LCAPH;
    int deg = e0 - s0; if (deg < 0) deg = 0;

    float a0=0.f, a1=0.f, a2=0.f, a3=0.f, dn=0.f;
    for (int j0 = 0; j0 < deg; j0 += 16){
      int jA = j0 + g, jB = j0 + 4 + g, jC = j0 + 8 + g, jD = j0 + 12 + g;
      float alA=0.f, alB=0.f, alC=0.f, alD=0.f;
      unsigned snA=0, snB=0, snC=0, snD=0;
      if (jA < deg){ uint2 r = lsev[s0+jA]; snA = r.x;
        alA = __half2float(((const __half*)&r.y)[h]); }
      if (jB < deg){ uint2 r = lsev[s0+jB]; snB = r.x;
        alB = __half2float(((const __half*)&r.y)[h]); }
      if (jC < deg){ uint2 r = lsev[s0+jC]; snC = r.x;
        alC = __half2float(((const __half*)&r.y)[h]); }
      if (jD < deg){ uint2 r = lsev[s0+jD]; snD = r.x;
        alD = __half2float(((const __half*)&r.y)[h]); }
      dn += alA + alB + alC + alD;
      uint2 vA = *(const uint2*)(feat16 + ((snA << 6) + co));
      uint2 vB = *(const uint2*)(feat16 + ((snB << 6) + co));
      uint2 vC = *(const uint2*)(feat16 + ((snC << 6) + co));
      uint2 vD = *(const uint2*)(feat16 + ((snD << 6) + co));
      float2 fA01 = __half22float2(*(const __half2*)&vA.x);
      float2 fA23 = __half22float2(*(const __half2*)&vA.y);
      float2 fB01 = __half22float2(*(const __half2*)&vB.x);
      float2 fB23 = __half22float2(*(const __half2*)&vB.y);
      float2 fC01 = __half22float2(*(const __half2*)&vC.x);
      float2 fC23 = __half22float2(*(const __half2*)&vC.y);
      float2 fD01 = __half22float2(*(const __half2*)&vD.x);
      float2 fD23 = __half22float2(*(const __half2*)&vD.y);
      a0 = fmaf(alA, fA01.x, a0); a0 = fmaf(alB, fB01.x, a0);
      a0 = fmaf(alC, fC01.x, a0); a0 = fmaf(alD, fD01.x, a0);
      a1 = fmaf(alA, fA01.y, a1); a1 = fmaf(alB, fB01.y, a1);
      a1 = fmaf(alC, fC01.y, a1); a1 = fmaf(alD, fD01.y, a1);
      a2 = fmaf(alA, fA23.x, a2); a2 = fmaf(alB, fB23.x, a2);
      a2 = fmaf(alC, fC23.x, a2); a2 = fmaf(alD, fD23.x, a2);
      a3 = fmaf(alA, fA23.y, a3); a3 = fmaf(alB, fB23.y, a3);
      a3 = fmaf(alC, fC23.y, a3); a3 = fmaf(alD, fD23.y, a3);
    }
    a0 += __shfl_xor(a0, 16); a1 += __shfl_xor(a1, 16);
    a2 += __shfl_xor(a2, 16); a3 += __shfl_xor(a3, 16);
    dn += __shfl_xor(dn, 16);
    a0 += __shfl_xor(a0, 32); a1 += __shfl_xor(a1, 32);
    a2 += __shfl_xor(a2, 32); a3 += __shfl_xor(a3, 32);
    dn += __shfl_xor(dn, 32);
    float rh = dn > 0.f ? 1.f/dn : 0.f;   // deferred softmax divide
    a0 = fmaf(a0, rh, b0v); a1 = fmaf(a1, rh, b1v);
    a2 = fmaf(a2, rh, b2v); a3 = fmaf(a3, rh, b3v);
    float h0 = 0.5f*(a0 + __shfl_xor(a0, 8)); h0 = fmaxf(h0, 0.f);
    float h1 = 0.5f*(a1 + __shfl_xor(a1, 8)); h1 = fmaxf(h1, 0.f);
    float h2 = 0.5f*(a2 + __shfl_xor(a2, 8)); h2 = fmaxf(h2, 0.f);
    float h3 = 0.5f*(a3 + __shfl_xor(a3, 8)); h3 = fmaxf(h3, 0.f);
    float r = h0*m0 + h1*m1 + h2*m2 + h3*m3;
    r += __shfl_xor(r, 4); r += __shfl_xor(r, 2); r += __shfl_xor(r, 1);
    if (lane == 0)      s1[node] = r;
    else if (lane == 8) s2[node] = r;
  }
}

// 8 edges per thread -> 16 independent gathers in flight.
__global__ __launch_bounds__(256) void edge_score_k(
                             const int* __restrict__ src, const int* __restrict__ dst,
                             const float* __restrict__ s1, const float* __restrict__ s2,
                             const float* __restrict__ ccomb, float* __restrict__ out){
  int i = blockIdx.x*blockDim.x + threadIdx.x;
  if (i >= N_EDGES/8) return;
  int4 sa = ((const int4*)src)[2*i],   sb = ((const int4*)src)[2*i+1];
  int4 da = ((const int4*)dst)[2*i],   db = ((const int4*)dst)[2*i+1];
  float v0 = s1[sa.x], v1 = s1[sa.y], v2 = s1[sa.z], v3 = s1[sa.w];
  float v4 = s1[sb.x], v5 = s1[sb.y], v6 = s1[sb.z], v7 = s1[sb.w];
  float u0 = s2[da.x], u1 = s2[da.y], u2 = s2[da.z], u3 = s2[da.w];
  float u4 = s2[db.x], u5 = s2[db.y], u6 = s2[db.z], u7 = s2[db.w];
  float c = ccomb[0];
  float4 oa, ob;
  oa.x = v0+u0+c; oa.y = v1+u1+c; oa.z = v2+u2+c; oa.w = v3+u3+c;
  ob.x = v4+u4+c; ob.y = v5+u5+c; ob.z = v6+u6+c; ob.w = v7+u7+c;
  ((float4*)out)[2*i]   = oa;
  ((float4*)out)[2*i+1] = ob;
}

extern "C" void kernel_launch(void* const* d_in, const int* in_sizes, int n_in,
                              void* d_out, int out_size, void* d_ws, size_t ws_size,
                              hipStream_t stream){
  const float* x      = (const float*)d_in[0];
  const float* W      = (const float*)d_in[1];
  const float* attn_l = (const float*)d_in[2];
  const float* attn_r = (const float*)d_in[3];
  const float* bias   = (const float*)d_in[4];
  const float* W1     = (const float*)d_in[5];
  const float* b1     = (const float*)d_in[6];
  const float* W2     = (const float*)d_in[7];
  const float* b2     = (const float*)d_in[8];
  const int*   src    = (const int*)d_in[9];
  const int*   dst    = (const int*)d_in[10];
  float* out = (float*)d_out;

  float* ws = (float*)d_ws;
  size_t off = 0;
  __half* feat16 = (__half*)(ws + off); off += (size_t)N_NODES*HO/2;
  float*  el     = ws + off; off += (size_t)N_NODES*HEADS;
  float*  er     = ws + off; off += (size_t)N_NODES*HEADS;
  float*  s1     = ws + off; off += N_NODES;
  float*  s2     = ws + off; off += N_NODES;
  float*  wcomb  = ws + off; off += 64;
  float*  ccomb  = ws + off; off += 64;
  int*    bstartT = (int*)(ws + off); off += (size_t)BIN_BLOCKS*NBUCK2;
  off = (off + 1) & ~(size_t)1;  // 8B align
  uint2*  stg    = (uint2*)(ws + off); off += (size_t)2*N_EDGES;

  feat_k<<<(N_NODES + 63)/64, 256, 0, stream>>>(x, W, attn_l, attn_r, feat16, el, er);
  binB_k<<<BIN_BLOCKS, BIN_THREADS, 0, stream>>>(src, dst, el, er, W1, b1, W2, b2,
                                                 bstartT, wcomb, ccomb, stg);
  scatter_agg_k<<<NBUCK2, 512, 0, stream>>>(bstartT, stg, feat16, bias, wcomb, s1, s2);
  edge_score_k<<<(N_EDGES/8 + 255)/256, 256, 0, stream>>>(src, dst, s1, s2, ccomb, out);
}

// Round 11
// 216.319 us; speedup vs baseline: 1.0758x; 1.0170x over previous
//
#include <hip/hip_runtime.h>
#include <hip/hip_fp16.h>

#define N_NODES 100000
#define N_EDGES 1600000
#define IN_F 128
#define OUT_F 32
#define HEADS 2
#define HO 64  // HEADS*OUT_F

#define NBUCK2 1563          // bucket = dst >> 6 (64-node slices)
#define BIN_BLOCKS 250
#define BIN_THREADS 1024
#define EPB (N_EDGES / BIN_BLOCKS)   // 6400 edges per bin block (exact)
#define NV4 (EPB/4)                  // 1600 int4 loads per block
#define LCAPH 1216           // per-bucket edge capacity: mean 1024, +6 sigma (proven R3-R10)
#define LPAD 2240            // padded sorted capacity: 1216 + 64*16 headroom

typedef __attribute__((ext_vector_type(8))) _Float16 half8;
typedef __attribute__((ext_vector_type(4))) _Float16 half4v;
typedef __attribute__((ext_vector_type(4))) float    f32x4;

#define XPAD 136   // 128 halves + 8 pad -> 272B row stride: 16B-aligned, 8-bank spread

// feat = x @ W via fp16 MFMA (16x16x32). Block: 256 thr / 4 waves, 64 nodes x 64 cols.
// W (32 KB fp32, L2-hot) is cast+transposed into LDS per block.
__global__ __launch_bounds__(256) void feat_k(
                       const float* __restrict__ x, const float* __restrict__ W,
                       const float* __restrict__ attn_l, const float* __restrict__ attn_r,
                       __half* __restrict__ feat16, float* __restrict__ el, float* __restrict__ er){
  __shared__ __align__(16) _Float16 Ws[64*XPAD];   // 17.4 KB  (B: W^T[c][k] fp16)
  __shared__ __align__(16) _Float16 xs[64*XPAD];   // 17.4 KB  (A: x[n][k] fp16)
  int tid = threadIdx.x;
  int node0 = blockIdx.x*64;

  // stage W: fp32 [k][c] -> fp16 Ws[c][k]
  for (int i = tid; i < 2048; i += 256){
    int k = i >> 4, c4 = (i & 15)*4;
    float4 v = ((const float4*)W)[i];
    Ws[(c4+0)*XPAD + k] = (_Float16)v.x;
    Ws[(c4+1)*XPAD + k] = (_Float16)v.y;
    Ws[(c4+2)*XPAD + k] = (_Float16)v.z;
    Ws[(c4+3)*XPAD + k] = (_Float16)v.w;
  }
  // stage x tile, fp32 -> fp16
  for (int i = tid; i < 2048; i += 256){
    int ln = i >> 5, kq = i & 31;
    int n = node0 + ln;
    float4 v = (n < N_NODES) ? ((const float4*)x)[(size_t)n*32 + kq]
                             : make_float4(0.f,0.f,0.f,0.f);
    half4v hv = { (_Float16)v.x, (_Float16)v.y, (_Float16)v.z, (_Float16)v.w };
    *(half4v*)&xs[ln*XPAD + kq*4] = hv;
  }
  __syncthreads();

  int w = tid >> 6, lane = tid & 63;
  int row_base = w*16;
  int lr = lane & 15, lg = lane >> 4;
  f32x4 acc0 = {0.f,0.f,0.f,0.f}, acc1 = {0.f,0.f,0.f,0.f};
  f32x4 acc2 = {0.f,0.f,0.f,0.f}, acc3 = {0.f,0.f,0.f,0.f};

  #pragma unroll
  for (int kk = 0; kk < 4; ++kk){
    int ko = kk*32 + lg*8;
    half8 a  = *(const half8*)&xs[(row_base + lr)*XPAD + ko];
    half8 b0 = *(const half8*)&Ws[( 0 + lr)*XPAD + ko];
    half8 b1 = *(const half8*)&Ws[(16 + lr)*XPAD + ko];
    half8 b2 = *(const half8*)&Ws[(32 + lr)*XPAD + ko];
    half8 b3 = *(const half8*)&Ws[(48 + lr)*XPAD + ko];
    acc0 = __builtin_amdgcn_mfma_f32_16x16x32_f16(a, b0, acc0, 0, 0, 0);
    acc1 = __builtin_amdgcn_mfma_f32_16x16x32_f16(a, b1, acc1, 0, 0, 0);
    acc2 = __builtin_amdgcn_mfma_f32_16x16x32_f16(a, b2, acc2, 0, 0, 0);
    acc3 = __builtin_amdgcn_mfma_f32_16x16x32_f16(a, b3, acc3, 0, 0, 0);
  }

  float al0 = attn_l[ 0 + lr], al1 = attn_l[16 + lr];
  float al2 = attn_l[32 + lr], al3 = attn_l[48 + lr];
  float ar0 = attn_r[ 0 + lr], ar1 = attn_r[16 + lr];
  float ar2 = attn_r[32 + lr], ar3 = attn_r[48 + lr];

  #pragma unroll
  for (int r = 0; r < 4; ++r){
    int n = node0 + row_base + lg*4 + r;
    float f0 = acc0[r], f1 = acc1[r], f2 = acc2[r], f3 = acc3[r];
    float p0 = f0*al0 + f1*al1, p1 = f2*al2 + f3*al3;
    float q0 = f0*ar0 + f1*ar1, q1 = f2*ar2 + f3*ar3;
    #pragma unroll
    for (int off = 1; off < 16; off <<= 1){
      p0 += __shfl_xor(p0, off); p1 += __shfl_xor(p1, off);
      q0 += __shfl_xor(q0, off); q1 += __shfl_xor(q1, off);
    }
    if (n < N_NODES){
      size_t base = (size_t)n*HO;
      feat16[base +  0 + lr] = __float2half_rn(f0);
      feat16[base + 16 + lr] = __float2half_rn(f1);
      feat16[base + 32 + lr] = __float2half_rn(f2);
      feat16[base + 48 + lr] = __float2half_rn(f3);
      if (lr == 0){
        *(float2*)&el[n*HEADS] = make_float2(p0, p1);
        *(float2*)&er[n*HEADS] = make_float2(q0, q1);
      }
    }
  }
}

// Fused bin: count -> in-LDS scan -> place. int4-vectorized edge loads,
// all el/er gathers issued before compute. Block-major dense CSR:
// block blk owns stg[blk*EPB .. +EPB) exclusively. Block 0 also folds
// wcomb = W1@W2 and ccomb = b1.W2+b2. bstart written TRANSPOSED
// (bucket-major rows) so scatter reads it coalesced.
__global__ __launch_bounds__(1024) void binB_k(const int* __restrict__ src,
                      const int* __restrict__ dst,
                      const float* __restrict__ el, const float* __restrict__ er,
                      const float* __restrict__ W1, const float* __restrict__ b1,
                      const float* __restrict__ W2, const float* __restrict__ b2,
                      int* __restrict__ bstartT, float* __restrict__ wcomb,
                      float* __restrict__ ccomb, uint2* __restrict__ stg){
  __shared__ int cnt[NBUCK2];
  int tid = threadIdx.x, blk = blockIdx.x;
  int lane = tid & 63, w = tid >> 6;
  if (blk == 0){
    if (tid < HO){
      float a = 0.f;
      for (int k = 0; k < OUT_F; ++k) a = fmaf(W1[tid*OUT_F + k], W2[k], a);
      wcomb[tid] = a;
    }
    if (tid == HO){
      float a = 0.f;
      for (int k = 0; k < OUT_F; ++k) a = fmaf(b1[k], W2[k], a);
      *ccomb = a + b2[0];
    }
  }
  for (int i = tid; i < NBUCK2; i += BIN_THREADS) cnt[i] = 0;
  __syncthreads();

  // load up to 8 edges per thread (2 x int4), batched
  int s_[8], d_[8];
  int ne = 0;
  const int4* s4p = (const int4*)(src + blk*EPB);
  const int4* d4p = (const int4*)(dst + blk*EPB);
  #pragma unroll
  for (int u = 0; u < 2; ++u){
    int i4 = tid + u*BIN_THREADS;
    if (i4 < NV4){
      int4 sv = s4p[i4], dv = d4p[i4];
      s_[4*u+0]=sv.x; s_[4*u+1]=sv.y; s_[4*u+2]=sv.z; s_[4*u+3]=sv.w;
      d_[4*u+0]=dv.x; d_[4*u+1]=dv.y; d_[4*u+2]=dv.z; d_[4*u+3]=dv.w;
      ne = 4*u+4;
    }
  }
  // issue all gathers (independent)
  float2 elv[8], erv[8];
  #pragma unroll
  for (int i = 0; i < 8; ++i){
    if (i < ne){
      elv[i] = *(const float2*)&el[s_[i]*HEADS];
      erv[i] = *(const float2*)&er[d_[i]*HEADS];
    }
  }
  // compute records + count
  unsigned rx[8], rex[8]; int rb[8];
  #pragma unroll
  for (int i = 0; i < 8; ++i){
    if (i < ne){
      float t0 = elv[i].x + erv[i].x, t1 = elv[i].y + erv[i].y;
      t0 = t0 > 0.f ? t0 : 0.2f*t0;
      t1 = t1 > 0.f ? t1 : 0.2f*t1;
      __half2 ex2 = __float22half2_rn(make_float2(__expf(t0), __expf(t1)));
      rb[i] = d_[i] >> 6;
      rx[i] = ((unsigned)s_[i] << 6) | (unsigned)(d_[i] & 63);
      rex[i] = *(const unsigned*)&ex2;
      atomicAdd(&cnt[rb[i]], 1);
    }
  }
  __syncthreads();

  // exclusive scan of cnt[NBUCK2] in place (wave 0, chunks of 64)
  if (w == 0){
    int run = 0;
    for (int c = 0; c < NBUCK2; c += 64){
      int i = c + lane;
      int v = (i < NBUCK2) ? cnt[i] : 0;
      int inc = v;
      #pragma unroll
      for (int off = 1; off < 64; off <<= 1){
        int t = __shfl_up(inc, off);
        if (lane >= off) inc += t;
      }
      if (i < NBUCK2) cnt[i] = run + inc - v;
      run += __shfl(inc, 63);
    }
  }
  __syncthreads();

  // emit per-block offsets, transposed (bucket-major rows)
  for (int i = tid; i < NBUCK2; i += BIN_THREADS)
    bstartT[(size_t)i*BIN_BLOCKS + blk] = cnt[i];
  __syncthreads();   // all reads of cnt done before phase 2 mutates it

  // place records (cnt reused as cursor)
  #pragma unroll
  for (int i = 0; i < 8; ++i){
    if (i < ne){
      int pos = atomicAdd(&cnt[rb[i]], 1);
      stg[(size_t)blk*EPB + pos] = make_uint2(rx[i], rex[i]);
    }
  }
}

// Fused scatter + aggregate (R10 structure + zero-alpha padding): single
// global pass staging; per-node counts padded to multiples of 16 and lsev
// pre-filled with {node0, alpha=0} records -> aggregate inner loop runs
// UNGUARDED (no per-slot compares/clamps).
__global__ void __launch_bounds__(512, 8) scatter_agg_k(
                              const int* __restrict__ bstartT, const uint2* __restrict__ stg,
                              const __half* __restrict__ feat16, const float* __restrict__ bias,
                              const float* __restrict__ wcomb,
                              float* __restrict__ s1, float* __restrict__ s2){
  __shared__ uint2 lraw[LCAPH];      // 9.5 KB
  __shared__ uint2 lsev[LPAD];       // 17.9 KB (padded sorted records)
  __shared__ int soff[BIN_BLOCKS];
  __shared__ int send[BIN_BLOCKS];
  __shared__ int segb[BIN_BLOCKS];
  __shared__ float wc[64];
  __shared__ int hist[64];
  __shared__ int start_[64];
  __shared__ int cur[64];
  __shared__ int hp[64];
  __shared__ int wtot[4];
  int b = blockIdx.x;
  int tid = threadIdx.x;
  int w = tid >> 6, lane = tid & 63;
  if (tid < 64){
    hist[tid] = 0;
    wc[tid] = wcomb[tid];
  }
  // pre-fill padded sorted array with zero-alpha records (node 0, ex=0)
  for (int i = tid; i < LPAD; i += 512) lsev[i] = make_uint2(0u, 0u);
  for (int i = tid; i < BIN_BLOCKS; i += 512){
    soff[i] = bstartT[(size_t)b*BIN_BLOCKS + i];
    send[i] = (b == NBUCK2-1) ? EPB : bstartT[(size_t)(b+1)*BIN_BLOCKS + i];
  }
  __syncthreads();

  // hierarchical exclusive scan of segment lengths -> segb
  int c_ = 0, inc = 0;
  if (tid < 256){
    if (tid < BIN_BLOCKS) c_ = send[tid] - soff[tid];
    inc = c_;
    #pragma unroll
    for (int off = 1; off < 64; off <<= 1){
      int t = __shfl_up(inc, off);
      if (lane >= off) inc += t;
    }
    if (lane == 63) wtot[w] = inc;
  }
  __syncthreads();
  if (tid == 0){
    int r = 0;
    #pragma unroll
    for (int i2 = 0; i2 < 4; ++i2){ int t = wtot[i2]; wtot[i2] = r; r += t; }
  }
  __syncthreads();
  if (tid < BIN_BLOCKS) segb[tid] = wtot[w] + inc - c_;
  __syncthreads();

  // compact copy global -> lraw (exact offsets, no atomics) + fused histogram
  int grp = tid >> 3, gl = tid & 7;
  for (int sg = grp; sg < BIN_BLOCKS; sg += 64){
    const uint2* seg = stg + (size_t)sg*EPB;
    int o = soff[sg], e = send[sg];
    int base = segb[sg] - o;
    for (int j = o + gl; j < e; j += 8){
      uint2 r = seg[j];
      int p = base + j;
      if (p < LCAPH){
        lraw[p] = r;
        atomicAdd(&hist[r.x & 63], 1);
      }
    }
  }
  __syncthreads();

  // exclusive scan of PADDED hist (multiples of 16) -> start_/cur, hp
  if (tid < 64){
    int v = hist[tid];
    int vp = (v + 15) & ~15;
    hp[tid] = vp;
    int inc2 = vp;
    #pragma unroll
    for (int off = 1; off < 64; off <<= 1){
      int t = __shfl_up(inc2, off);
      if (lane >= off) inc2 += t;
    }
    start_[tid] = inc2 - vp;
    cur[tid] = inc2 - vp;
  }
  __syncthreads();

  // LDS reorder raw -> padded-sorted by local node (pad slots keep {0,0})
  int tot = segb[BIN_BLOCKS-1] + (send[BIN_BLOCKS-1] - soff[BIN_BLOCKS-1]);
  if (tot > LCAPH) tot = LCAPH;
  for (int i = tid; i < tot; i += 512){
    uint2 r = lraw[i];
    int pos = atomicAdd(&cur[r.x & 63], 1);
    if (pos < LPAD) lsev[pos] = make_uint2(r.x >> 6, r.y);
  }
  __syncthreads();

  // aggregate: wave w handles local nodes w*8 .. w*8+7; 16 edges in flight,
  // loop fully unguarded (padded with zero-alpha records).
  int g  = lane >> 4;
  int c4 = lane & 15;
  int h  = (c4 >= 8);
  float b0v = bias[c4*4 + 0], b1v = bias[c4*4 + 1], b2v = bias[c4*4 + 2], b3v = bias[c4*4 + 3];
  int f0 = (c4 & 7)*4;
  int wo = (h ? 32 : 0) + f0;   // lanes c4<8 compute MLP row 0 (s1), c4>=8 row 1 (s2)
  float m0 = wc[wo], m1 = wc[wo+1], m2 = wc[wo+2], m3 = wc[wo+3];
  unsigned co = (unsigned)(c4*4);
  for (int i = 0; i < 8; ++i){
    int nl = w*8 + i;
    int node = b*64 + nl;
    if (node >= N_NODES) break;
    int s0 = start_[nl];
    int dp = hp[nl];

    float a0=0.f, a1=0.f, a2=0.f, a3=0.f, dn=0.f;
    for (int j0 = 0; j0 < dp; j0 += 16){
      uint2 rA = lsev[s0 + j0 + g];
      uint2 rB = lsev[s0 + j0 + 4 + g];
      uint2 rC = lsev[s0 + j0 + 8 + g];
      uint2 rD = lsev[s0 + j0 + 12 + g];
      float alA = __half2float(((const __half*)&rA.y)[h]);
      float alB = __half2float(((const __half*)&rB.y)[h]);
      float alC = __half2float(((const __half*)&rC.y)[h]);
      float alD = __half2float(((const __half*)&rD.y)[h]);
      dn += alA + alB + alC + alD;
      uint2 vA = *(const uint2*)(feat16 + (((unsigned)rA.x << 6) + co));
      uint2 vB = *(const uint2*)(feat16 + (((unsigned)rB.x << 6) + co));
      uint2 vC = *(const uint2*)(feat16 + (((unsigned)rC.x << 6) + co));
      uint2 vD = *(const uint2*)(feat16 + (((unsigned)rD.x << 6) + co));
      float2 fA01 = __half22float2(*(const __half2*)&vA.x);
      float2 fA23 = __half22float2(*(const __half2*)&vA.y);
      float2 fB01 = __half22float2(*(const __half2*)&vB.x);
      float2 fB23 = __half22float2(*(const __half2*)&vB.y);
      float2 fC01 = __half22float2(*(const __half2*)&vC.x);
      float2 fC23 = __half22float2(*(const __half2*)&vC.y);
      float2 fD01 = __half22float2(*(const __half2*)&vD.x);
      float2 fD23 = __half22float2(*(const __half2*)&vD.y);
      a0 = fmaf(alA, fA01.x, a0); a0 = fmaf(alB, fB01.x, a0);
      a0 = fmaf(alC, fC01.x, a0); a0 = fmaf(alD, fD01.x, a0);
      a1 = fmaf(alA, fA01.y, a1); a1 = fmaf(alB, fB01.y, a1);
      a1 = fmaf(alC, fC01.y, a1); a1 = fmaf(alD, fD01.y, a1);
      a2 = fmaf(alA, fA23.x, a2); a2 = fmaf(alB, fB23.x, a2);
      a2 = fmaf(alC, fC23.x, a2); a2 = fmaf(alD, fD23.x, a2);
      a3 = fmaf(alA, fA23.y, a3); a3 = fmaf(alB, fB23.y, a3);
      a3 = fmaf(alC, fC23.y, a3); a3 = fmaf(alD, fD23.y, a3);
    }
    a0 += __shfl_xor(a0, 16); a1 += __shfl_xor(a1, 16);
    a2 += __shfl_xor(a2, 16); a3 += __shfl_xor(a3, 16);
    dn += __shfl_xor(dn, 16);
    a0 += __shfl_xor(a0, 32); a1 += __shfl_xor(a1, 32);
    a2 += __shfl_xor(a2, 32); a3 += __shfl_xor(a3, 32);
    dn += __shfl_xor(dn, 32);
    float rh = dn > 0.f ? 1.f/dn : 0.f;   // deferred softmax divide
    a0 = fmaf(a0, rh, b0v); a1 = fmaf(a1, rh, b1v);
    a2 = fmaf(a2, rh, b2v); a3 = fmaf(a3, rh, b3v);
    float h0 = 0.5f*(a0 + __shfl_xor(a0, 8)); h0 = fmaxf(h0, 0.f);
    float h1 = 0.5f*(a1 + __shfl_xor(a1, 8)); h1 = fmaxf(h1, 0.f);
    float h2 = 0.5f*(a2 + __shfl_xor(a2, 8)); h2 = fmaxf(h2, 0.f);
    float h3 = 0.5f*(a3 + __shfl_xor(a3, 8)); h3 = fmaxf(h3, 0.f);
    float r = h0*m0 + h1*m1 + h2*m2 + h3*m3;
    r += __shfl_xor(r, 4); r += __shfl_xor(r, 2); r += __shfl_xor(r, 1);
    if (lane == 0)      s1[node] = r;
    else if (lane == 8) s2[node] = r;
  }
}

// 8 edges per thread -> 16 independent gathers in flight.
__global__ __launch_bounds__(256) void edge_score_k(
                             const int* __restrict__ src, const int* __restrict__ dst,
                             const float* __restrict__ s1, const float* __restrict__ s2,
                             const float* __restrict__ ccomb, float* __restrict__ out){
  int i = blockIdx.x*blockDim.x + threadIdx.x;
  if (i >= N_EDGES/8) return;
  int4 sa = ((const int4*)src)[2*i],   sb = ((const int4*)src)[2*i+1];
  int4 da = ((const int4*)dst)[2*i],   db = ((const int4*)dst)[2*i+1];
  float v0 = s1[sa.x], v1 = s1[sa.y], v2 = s1[sa.z], v3 = s1[sa.w];
  float v4 = s1[sb.x], v5 = s1[sb.y], v6 = s1[sb.z], v7 = s1[sb.w];
  float u0 = s2[da.x], u1 = s2[da.y], u2 = s2[da.z], u3 = s2[da.w];
  float u4 = s2[db.x], u5 = s2[db.y], u6 = s2[db.z], u7 = s2[db.w];
  float c = ccomb[0];
  float4 oa, ob;
  oa.x = v0+u0+c; oa.y = v1+u1+c; oa.z = v2+u2+c; oa.w = v3+u3+c;
  ob.x = v4+u4+c; ob.y = v5+u5+c; ob.z = v6+u6+c; ob.w = v7+u7+c;
  ((float4*)out)[2*i]   = oa;
  ((float4*)out)[2*i+1] = ob;
}

extern "C" void kernel_launch(void* const* d_in, const int* in_sizes, int n_in,
                              void* d_out, int out_size, void* d_ws, size_t ws_size,
                              hipStream_t stream){
  const float* x      = (const float*)d_in[0];
  const float* W      = (const float*)d_in[1];
  const float* attn_l = (const float*)d_in[2];
  const float* attn_r = (const float*)d_in[3];
  const float* bias   = (const float*)d_in[4];
  const float* W1     = (const float*)d_in[5];
  const float* b1     = (const float*)d_in[6];
  const float* W2     = (const float*)d_in[7];
  const float* b2     = (const float*)d_in[8];
  const int*   src    = (const int*)d_in[9];
  const int*   dst    = (const int*)d_in[10];
  float* out = (float*)d_out;

  float* ws = (float*)d_ws;
  size_t off = 0;
  __half* feat16 = (__half*)(ws + off); off += (size_t)N_NODES*HO/2;
  float*  el     = ws + off; off += (size_t)N_NODES*HEADS;
  float*  er     = ws + off; off += (size_t)N_NODES*HEADS;
  float*  s1     = ws + off; off += N_NODES;
  float*  s2     = ws + off; off += N_NODES;
  float*  wcomb  = ws + off; off += 64;
  float*  ccomb  = ws + off; off += 64;
  int*    bstartT = (int*)(ws + off); off += (size_t)BIN_BLOCKS*NBUCK2;
  off = (off + 1) & ~(size_t)1;  // 8B align
  uint2*  stg    = (uint2*)(ws + off); off += (size_t)2*N_EDGES;

  feat_k<<<(N_NODES + 63)/64, 256, 0, stream>>>(x, W, attn_l, attn_r, feat16, el, er);
  binB_k<<<BIN_BLOCKS, BIN_THREADS, 0, stream>>>(src, dst, el, er, W1, b1, W2, b2,
                                                 bstartT, wcomb, ccomb, stg);
  scatter_agg_k<<<NBUCK2, 512, 0, stream>>>(bstartT, stg, feat16, bias, wcomb, s1, s2);
  edge_score_k<<<(N_EDGES/8 + 255)/256, 256, 0, stream>>>(src, dst, s1, s2, ccomb, out);
}